// Round 21
// baseline (209.640 us; speedup 1.0000x reference)
//
#include <hip/hip_runtime.h>
#include <hip/hip_bf16.h>
#include <hip/hip_fp8.h>

// Problem constants
#define B_ 2
#define S_ 2048
#define D_ 256
#define H_ 8
#define E_ 256
#define F_ 1024

typedef __attribute__((ext_vector_type(8))) __bf16 b16x8;
typedef __attribute__((ext_vector_type(4))) __bf16 b16x4;
typedef __attribute__((ext_vector_type(4))) float f32x4;
typedef __attribute__((ext_vector_type(2))) float f32x2;

__device__ inline float wred_sum(float v) {
#pragma unroll
  for (int o = 32; o > 0; o >>= 1) v += __shfl_xor(v, o);
  return v;
}

__device__ inline unsigned char f8(float v) {
  return __hip_fp8_e4m3(v).__x;
}
__device__ inline float e4f(unsigned char u) {
  __hip_fp8_e4m3 t;
  t.__x = (__hip_fp8_storage_t)u;
  return (float)t;
}

// HW fp8 pack/unpack (gfx950); HI must be a compile-time constant (instr modifier)
template <bool HI>
__device__ inline unsigned f8pack2(float a, float b, unsigned old) {
#if __has_builtin(__builtin_amdgcn_cvt_pk_fp8_f32)
  return (unsigned)__builtin_amdgcn_cvt_pk_fp8_f32(a, b, (int)old, HI);
#else
  unsigned lo = (unsigned)f8(a) | ((unsigned)f8(b) << 8);
  return HI ? ((old & 0x0000FFFFu) | (lo << 16)) : ((old & 0xFFFF0000u) | lo);
#endif
}
template <bool HI>
__device__ inline f32x2 f8unpack2(unsigned u) {
#if __has_builtin(__builtin_amdgcn_cvt_pk_f32_fp8)
  return __builtin_amdgcn_cvt_pk_f32_fp8((int)u, HI);
#else
  f32x2 r;
  unsigned s = HI ? (u >> 16) : u;
  r[0] = e4f(s & 255);
  r[1] = e4f((s >> 8) & 255);
  return r;
#endif
}

// chunk swizzle for fp8 tiles (8B chunks): bijective, spreads banks by row
#define SWC(ch, row) ((ch) ^ (((row) & 15) << 1))

// ---------------- LayerNorm (+cast to bf16): one row of 256 per wave ----------------
__device__ inline void ln_row(const float* __restrict__ x, const float* __restrict__ scale,
                              const float* __restrict__ bias, __bf16* __restrict__ out,
                              int row, int lane) {
  const float4 v = *(const float4*)(x + (size_t)row * D_ + lane * 4);
  float s = v.x + v.y + v.z + v.w;
  float q = v.x * v.x + v.y * v.y + v.z * v.z + v.w * v.w;
  s = wred_sum(s);
  q = wred_sum(q);
  const float mean = s * (1.0f / D_);
  const float var = q * (1.0f / D_) - mean * mean;
  const float rstd = rsqrtf(var + 1e-6f);
  const float4 sc = *(const float4*)(scale + lane * 4);
  const float4 bi = *(const float4*)(bias + lane * 4);
  b16x4 o;
  o[0] = (__bf16)((v.x - mean) * rstd * sc.x + bi.x);
  o[1] = (__bf16)((v.y - mean) * rstd * sc.y + bi.y);
  o[2] = (__bf16)((v.z - mean) * rstd * sc.z + bi.z);
  o[3] = (__bf16)((v.w - mean) * rstd * sc.w + bi.w);
  *(b16x4*)(out + (size_t)row * D_ + lane * 4) = o;
}

__global__ __launch_bounds__(256) void ln_cast_kernel(
    const float* __restrict__ x, const float* __restrict__ scale,
    const float* __restrict__ bias, __bf16* __restrict__ out) {
  ln_row(x, scale, bias, out, blockIdx.x * 4 + (threadIdx.x >> 6), threadIdx.x & 63);
}

// ---------------- Weight transpose-cast + LN1 + out-init ----------------
// bid<640: 64x64 weight tiles. [640,1664): LN1 rows. [1664,2688): out = x + bo.
__global__ __launch_bounds__(256) void trans_cast(
    const float* wq, const float* wk, const float* wv, const float* wo,
    const float* w1, const float* w2,
    __bf16* wqT, __bf16* wkT, __bf16* wvT, __bf16* woT, __bf16* w1T, __bf16* w2T,
    const float* x, const float* ln1s, const float* ln1b, __bf16* xln,
    const float* bo, float* outp) {
  __shared__ float lds[64][65];
  int bid = blockIdx.x;
  const int t = threadIdx.x;
  if (bid >= 1664) {  // out init: out = x + bo (1M floats, float4)
    const int i = (bid - 1664) * 256 + t;
    const float4 xb = ((const float4*)x)[i];
    const float4 bb = ((const float4*)bo)[i & 63];
    float4 o;
    o.x = xb.x + bb.x; o.y = xb.y + bb.y; o.z = xb.z + bb.z; o.w = xb.w + bb.w;
    ((float4*)outp)[i] = o;
    return;
  }
  if (bid >= 640) {  // LN1: 4 rows per block
    ln_row(x, ln1s, ln1b, xln, (bid - 640) * 4 + (t >> 6), t & 63);
    return;
  }
  const float* in;
  __bf16* out;
  int R, C, tidx;
  if (bid < 128) { in = wq; out = wqT; R = 256; C = 2048; tidx = bid; }
  else if (bid < 256) { in = wk; out = wkT; R = 256; C = 2048; tidx = bid - 128; }
  else if (bid < 384) { in = wv; out = wvT; R = 256; C = 2048; tidx = bid - 256; }
  else if (bid < 512) { in = wo; out = woT; R = 2048; C = 256; tidx = bid - 384; }
  else if (bid < 576) { in = w1; out = w1T; R = 256; C = 1024; tidx = bid - 512; }
  else { in = w2; out = w2T; R = 1024; C = 256; tidx = bid - 576; }
  const int tiles_c = C >> 6;
  const int tr = tidx / tiles_c, tc = tidx % tiles_c;
  const int r = t >> 2, cq = t & 3;
  const float* base = in + (size_t)(tr * 64 + r) * C + tc * 64 + cq * 16;
#pragma unroll
  for (int i = 0; i < 4; ++i) {
    const float4 v = ((const float4*)base)[i];
    lds[r][cq * 16 + i * 4 + 0] = v.x;
    lds[r][cq * 16 + i * 4 + 1] = v.y;
    lds[r][cq * 16 + i * 4 + 2] = v.z;
    lds[r][cq * 16 + i * 4 + 3] = v.w;
  }
  __syncthreads();
  const int oc = t >> 2;
  __bf16* ob = out + (size_t)(tc * 64 + oc) * R + tr * 64 + cq * 16;
  b16x8 o0, o1;
#pragma unroll
  for (int i = 0; i < 8; ++i) o0[i] = (__bf16)lds[cq * 16 + i][oc];
#pragma unroll
  for (int i = 0; i < 8; ++i) o1[i] = (__bf16)lds[cq * 16 + 8 + i][oc];
  ((b16x8*)ob)[0] = o0;
  ((b16x8*)ob)[1] = o1;
}

__device__ inline float gelu_f(float u) {
  const float c = 0.7978845608028654f;  // sqrt(2/pi)
  float t = tanhf(c * (u + 0.044715f * u * u * u));
  return 0.5f * u * (1.0f + t);
}

// ---------------- NT GEMM: C = A(MxK) * Bt(NxK)^T, bf16 MFMA, fp32 acc ----------------
// EPI: 5=fc1 gelu(acc+bias)->bf16 (ld F)
//      6=K proj -> fp8-packed K8 (+z*4MB batch offset)
//      7=split-K partial f32 (z = split index)
//      8=V proj -> fp8-packed V8 (+z*4MB batch offset)
#define BN 128
#define BK 64

template <int EPI, int MT, typename TA>
__global__ __launch_bounds__(256) void gemm_nt(
    const TA* __restrict__ A, const __bf16* __restrict__ Bt,
    const float* __restrict__ bias, void* __restrict__ Cout,
    int K, int lda, int ldb, long strideAz, long strideBz) {
  constexpr int BM = MT * 32;
  __shared__ __attribute__((aligned(16))) __bf16 As[BM * BK];
  __shared__ __attribute__((aligned(16))) __bf16 Bs[BN * BK];
  const int tid = threadIdx.x;
  const int lane = tid & 63;
  const int wid = tid >> 6;
  const int wr = wid >> 1, wc = wid & 1;
  const int m0 = blockIdx.y * BM, n0 = blockIdx.x * BN;
  const TA* Ab = A + (size_t)blockIdx.z * strideAz;
  const __bf16* Btb = Bt + (size_t)blockIdx.z * strideBz;

  f32x4 acc[MT][4] = {};

  for (int k0 = 0; k0 < K; k0 += BK) {
    __syncthreads();
#pragma unroll
    for (int i = 0; i < MT; ++i) {
      const int cid = tid + i * 256;
      const int row = cid >> 3, ch = cid & 7;
      const int sw = ch ^ (row & 7);
      b16x8 av = *(const b16x8*)(Ab + (size_t)(m0 + row) * lda + k0 + ch * 8);
      *(b16x8*)(As + row * BK + sw * 8) = av;
    }
#pragma unroll
    for (int i = 0; i < 4; ++i) {
      const int cid = tid + i * 256;
      const int row = cid >> 3, ch = cid & 7;
      const int sw = ch ^ (row & 7);
      const b16x8 bv = *(const b16x8*)(Btb + (size_t)(n0 + row) * ldb + k0 + ch * 8);
      *(b16x8*)(Bs + row * BK + sw * 8) = bv;
    }
    __syncthreads();
#pragma unroll
    for (int ks = 0; ks < 2; ++ks) {
      b16x8 af[MT], bfr[4];
#pragma unroll
      for (int m = 0; m < MT; ++m) {
        const int r = wr * (MT * 16) + m * 16 + (lane & 15);
        const int ch = ks * 4 + (lane >> 4);
        af[m] = *(const b16x8*)(As + r * BK + (ch ^ (r & 7)) * 8);
      }
#pragma unroll
      for (int n = 0; n < 4; ++n) {
        const int r = wc * 64 + n * 16 + (lane & 15);
        const int ch = ks * 4 + (lane >> 4);
        bfr[n] = *(const b16x8*)(Bs + r * BK + (ch ^ (r & 7)) * 8);
      }
#pragma unroll
      for (int m = 0; m < MT; ++m)
#pragma unroll
        for (int n = 0; n < 4; ++n)
          acc[m][n] = __builtin_amdgcn_mfma_f32_16x16x32_bf16(af[m], bfr[n],
                                                              acc[m][n], 0, 0, 0);
    }
  }

  const int z = blockIdx.z;
#pragma unroll
  for (int m = 0; m < MT; ++m) {
    const int gr0 = m0 + wr * (MT * 16) + m * 16 + (lane >> 4) * 4;
#pragma unroll
    for (int n = 0; n < 4; ++n) {
      const int gc = n0 + wc * 64 + n * 16 + (lane & 15);
#pragma unroll
      for (int r = 0; r < 4; ++r) {
        float v = acc[m][n][r];
        const int grow = gr0 + r;
        if constexpr (EPI == 5) {
          ((__bf16*)Cout)[(size_t)grow * F_ + gc] = (__bf16)gelu_f(v + bias[gc]);
        } else if constexpr (EPI == 6) {
          v += bias[gc];
          const int hh = gc >> 8, e = gc & 255, key = grow;
          const size_t addr =
              ((((size_t)hh * 128 + (key >> 4)) * 8 + (e >> 5)) * 64 +
               (((e >> 3) & 3) * 16 + (key & 15))) * 8 + (e & 7);
          ((unsigned char*)Cout)[(size_t)z * 4194304 + addr] = f8(v);
        } else if constexpr (EPI == 8) {
          v += bias[grow];
          const int hh = grow >> 8, e = grow & 255, key = gc;
          const size_t addr =
              ((((size_t)hh * 16 + (e >> 4)) * 64 + (key >> 5)) * 64 +
               (((key >> 3) & 3) * 16 + (e & 15))) * 8 + (key & 7);
          ((unsigned char*)Cout)[(size_t)z * 4194304 + addr] = f8(v);
        } else {  // 7: split-K partial
          ((float*)Cout)[((size_t)z * gridDim.y * BM + grow) * 256 + gc] = v;
        }
      }
    }
  }
}

// ---------------- Fused flash attention + WO partial: 32 q-rows, 8 waves, fp8 ----------------
// 512 threads, grid 1024 = both batches. XCD-affine: h = bid&7; b = (bid>>3)&1; m0 = (bid>>4)*32.
// LDS ~73KB -> 2 blocks/CU (4 waves/SIMD): cross-block phase overlap hides barrier drains
// (retry of round-14 geometry now that spills, NT stores, and software f8 are all fixed).
__global__ __launch_bounds__(512, 4) void attn_fused(
    const __bf16* __restrict__ xln, const __bf16* __restrict__ wqT,
    const float* __restrict__ bq, const unsigned char* __restrict__ k8,
    const unsigned char* __restrict__ v8, const __bf16* __restrict__ woT,
    float* __restrict__ attn, float* __restrict__ out) {
  __shared__ __attribute__((aligned(16))) unsigned char p_s[32 * 2048];  // 64 KB (vb overlays)
  __shared__ __attribute__((aligned(16))) unsigned char q_s[32 * 256];   // 8 KB
  __shared__ float l_s[32][9];
  __shared__ float inv_s[32];
  __bf16* vb = (__bf16*)p_s;  // val (32x256 bf16 = 16KB) overlays p_s after P2 reads

  const int tid = threadIdx.x, lane = tid & 63, wid = tid >> 6;
  const int h = blockIdx.x & 7;
  const int b = (blockIdx.x >> 3) & 1;
  const int m0 = (blockIdx.x >> 4) * 32;
  const int l15 = lane & 15, l4 = lane >> 4;
  const int e0w = wid * 32;
  const __bf16* xln_b = xln + (size_t)b * S_ * D_;
  float* attn_b = attn + (size_t)b * H_ * S_ * S_;
  float* out_b = out + (size_t)b * S_ * D_;
  const unsigned char* khp = k8 + (size_t)b * 4194304 + (size_t)h * 524288;
  const unsigned char* vhp = v8 + (size_t)b * 4194304 + (size_t)h * 524288;

  // ---- P0 (swapped): q(32xE) -> q_s fp8, packed u32 stores ----
  {
    f32x4 aq[2][2] = {};  // [m: q-tile][n: e-tile]; D[e_local][q]
#pragma unroll
    for (int ks = 0; ks < 8; ++ks) {
      const int d0 = ks * 32 + l4 * 8;
      b16x8 aw[2], bx[2];
#pragma unroll
      for (int n = 0; n < 2; ++n)
        aw[n] = *(const b16x8*)(wqT + (size_t)(h * E_ + e0w + n * 16 + l15) * D_ + d0);
#pragma unroll
      for (int m = 0; m < 2; ++m)
        bx[m] = *(const b16x8*)(xln_b + (size_t)(m0 + m * 16 + l15) * D_ + d0);
#pragma unroll
      for (int m = 0; m < 2; ++m)
#pragma unroll
        for (int n = 0; n < 2; ++n)
          aq[m][n] = __builtin_amdgcn_mfma_f32_16x16x32_bf16(aw[n], bx[m], aq[m][n], 0, 0, 0);
    }
#pragma unroll
    for (int m = 0; m < 2; ++m)
#pragma unroll
      for (int n = 0; n < 2; ++n) {
        const int row = m * 16 + l15;               // q-row
        const int e = e0w + n * 16 + l4 * 4;        // 4 consecutive e
        unsigned u = f8pack2<false>(aq[m][n][0] + bq[h * E_ + e],
                                    aq[m][n][1] + bq[h * E_ + e + 1], 0u);
        u = f8pack2<true>(aq[m][n][2] + bq[h * E_ + e + 2],
                          aq[m][n][3] + bq[h * E_ + e + 3], u);
        *(unsigned*)(q_s + row * 256 + SWC(e >> 3, row) * 8 + (e & 7)) = u;
      }
  }
  __syncthreads();

  // ---- P1 (swapped): S^T = K.Q -> P~ fp8 packed u32; 4 chunks of 64 keys ----
  float lsum[2] = {};
  for (int kc = 0; kc < 4; ++kc) {
    const int kb = wid * 256 + kc * 64;
    const int kt0 = kb >> 4;
    f32x4 acc1[2][4] = {};  // [m: q-tile][n: key-tile]; 32 VGPRs live
#pragma unroll
    for (int ks = 0; ks < 8; ++ks) {
      long long ak[4], qf[2];
#pragma unroll
      for (int n = 0; n < 4; ++n)
        ak[n] = *(const long long*)(khp + ((size_t)(kt0 + n) * 8 + ks) * 512 + lane * 8);
#pragma unroll
      for (int m = 0; m < 2; ++m) {
        const int row = m * 16 + l15;
        qf[m] = *(const long long*)(q_s + row * 256 + SWC(ks * 4 + l4, row) * 8);
      }
      __builtin_amdgcn_s_setprio(1);
#pragma unroll
      for (int m = 0; m < 2; ++m)
#pragma unroll
        for (int n = 0; n < 4; ++n)
          acc1[m][n] = __builtin_amdgcn_mfma_f32_16x16x32_fp8_fp8(ak[n], qf[m],
                                                                  acc1[m][n], 0, 0, 0);
      __builtin_amdgcn_s_setprio(0);
    }
#pragma unroll
    for (int m = 0; m < 2; ++m) {
      const int row = m * 16 + l15;  // q-row
#pragma unroll
      for (int n = 0; n < 4; ++n) {
        const int key = kb + n * 16 + l4 * 4;  // 4 consecutive keys
        const float p0 = __expf(acc1[m][n][0] * 0.0625f);
        const float p1 = __expf(acc1[m][n][1] * 0.0625f);
        const float p2 = __expf(acc1[m][n][2] * 0.0625f);
        const float p3 = __expf(acc1[m][n][3] * 0.0625f);
        unsigned u = f8pack2<false>(p0, p1, 0u);
        u = f8pack2<true>(p2, p3, u);
        *(unsigned*)(p_s + row * 2048 + SWC(key >> 3, row) * 8 + (key & 7)) = u;
        lsum[m] += (p0 + p1) + (p2 + p3);
      }
    }
  }
#pragma unroll
  for (int m = 0; m < 2; ++m) {
    float s = lsum[m];
    s += __shfl_xor(s, 16);
    s += __shfl_xor(s, 32);
    if (l4 == 0) l_s[m * 16 + l15][wid] = s;
  }
  __syncthreads();
  if (tid < 32) {
    float s = 0.f;
#pragma unroll
    for (int w = 0; w < 8; ++w) s += l_s[tid][w];
    inv_s[tid] = 1.0f / s;
  }
  __syncthreads();

  // ---- P2: PV fp8 (wave owns 32 e-cols) + interleaved normalized-attn writes ----
  f32x4 acc2[2][2] = {};
  {
    const int prow = tid >> 4, pc = tid & 15;  // 16 thr/row; 16 slices of 8 keys each
    const float pinv = inv_s[prow];
    float* arow = attn_b + ((size_t)h * S_ + m0 + prow) * S_;
#pragma unroll 2
    for (int kt = 0; kt < 64; ++kt) {
      long long paf[2], bvf[2];
#pragma unroll
      for (int m = 0; m < 2; ++m) {
        const int row = m * 16 + l15;
        paf[m] = *(const long long*)(p_s + row * 2048 + SWC(kt * 4 + l4, row) * 8);
      }
#pragma unroll
      for (int n = 0; n < 2; ++n)
        bvf[n] = *(const long long*)(vhp + ((size_t)(wid * 2 + n) * 64 + kt) * 512 + lane * 8);
      __builtin_amdgcn_s_setprio(1);
#pragma unroll
      for (int m = 0; m < 2; ++m)
#pragma unroll
        for (int n = 0; n < 2; ++n)
          acc2[m][n] = __builtin_amdgcn_mfma_f32_16x16x32_fp8_fp8(paf[m], bvf[n],
                                                                  acc2[m][n], 0, 0, 0);
      __builtin_amdgcn_s_setprio(0);

      if ((kt & 3) == 0) {  // one 8-key slice per 4 PV iterations (16 total)
        const int ch = pc + (kt >> 2) * 16;
        const unsigned* pu = (const unsigned*)(p_s + prow * 2048 + SWC(ch, prow) * 8);
        const unsigned u0 = pu[0], u1 = pu[1];
        const f32x2 a0 = f8unpack2<false>(u0), a1 = f8unpack2<true>(u0);
        const f32x2 a2 = f8unpack2<false>(u1), a3 = f8unpack2<true>(u1);
        f32x4 o0, o1;
        o0[0] = a0[0] * pinv; o0[1] = a0[1] * pinv;
        o0[2] = a1[0] * pinv; o0[3] = a1[1] * pinv;
        o1[0] = a2[0] * pinv; o1[1] = a2[1] * pinv;
        o1[2] = a3[0] * pinv; o1[3] = a3[1] * pinv;
        const int key0 = ch * 8;
        *(f32x4*)(arow + key0) = o0;       // plain cached store (L2 write-combining)
        *(f32x4*)(arow + key0 + 4) = o1;
      }
    }
  }
  __syncthreads();  // all p_s reads done before vb (alias) is written

#pragma unroll
  for (int m = 0; m < 2; ++m)
#pragma unroll
    for (int n = 0; n < 2; ++n)
#pragma unroll
      for (int r = 0; r < 4; ++r) {
        const int row = m * 16 + l4 * 4 + r;
        const int e = e0w + n * 16 + l15;
        vb[row * 256 + (e ^ ((row & 7) << 3))] = (__bf16)(acc2[m][n][r] * inv_s[row]);
      }
  __syncthreads();  // vb read cross-wave below

  // ---- P2b: WO partial (bf16): wave owns 32 d-cols, K = full 256 e ----
  {
    f32x4 acc3[2][2] = {};
#pragma unroll
    for (int ks = 0; ks < 8; ++ks) {
      const int ch = ks * 4 + l4;
      b16x8 vaf[2], wf[2];
#pragma unroll
      for (int m = 0; m < 2; ++m) {
        const int row = m * 16 + l15;
        vaf[m] = *(const b16x8*)(vb + row * 256 + ((ch ^ (row & 7)) * 8));
      }
      const int ec = ks * 32 + l4 * 8;
#pragma unroll
      for (int n = 0; n < 2; ++n)
        wf[n] = *(const b16x8*)(woT + (size_t)(e0w + n * 16 + l15) * 2048 + h * E_ + ec);
#pragma unroll
      for (int m = 0; m < 2; ++m)
#pragma unroll
        for (int n = 0; n < 2; ++n)
          acc3[m][n] = __builtin_amdgcn_mfma_f32_16x16x32_bf16(vaf[m], wf[n], acc3[m][n], 0, 0, 0);
    }
#pragma unroll
    for (int m = 0; m < 2; ++m)
#pragma unroll
      for (int n = 0; n < 2; ++n)
#pragma unroll
        for (int r = 0; r < 4; ++r) {
          const int row = m * 16 + l4 * 4 + r;
          const int d = e0w + n * 16 + l15;
          atomicAdd(out_b + (size_t)(m0 + row) * D_ + d, acc3[m][n][r]);
        }
  }
}

// ---------------- out = resid + bias + sum_z pbuf[z] (N=256 cols) ----------------
__global__ __launch_bounds__(256) void reduce_addk(
    const float* __restrict__ pbuf, const float* __restrict__ resid,
    const float* __restrict__ bias, float* __restrict__ out, int mn4, int kz) {
  const int i = blockIdx.x * 256 + threadIdx.x;
  if (i >= mn4) return;
  float4 s = ((const float4*)resid)[i];
  const float4 bb = ((const float4*)bias)[i & 63];
  s.x += bb.x; s.y += bb.y; s.z += bb.z; s.w += bb.w;
  for (int z = 0; z < kz; ++z) {
    const float4 p = ((const float4*)pbuf)[(size_t)z * mn4 + i];
    s.x += p.x; s.y += p.y; s.z += p.z; s.w += p.w;
  }
  ((float4*)out)[i] = s;
}

extern "C" void kernel_launch(void* const* d_in, const int* in_sizes, int n_in,
                              void* d_out, int out_size, void* d_ws, size_t ws_size,
                              hipStream_t stream) {
  (void)in_sizes; (void)n_in; (void)out_size; (void)ws_size;
  const float* x    = (const float*)d_in[0];
  const float* ln1s = (const float*)d_in[1];
  const float* ln1b = (const float*)d_in[2];
  const float* wq   = (const float*)d_in[3];
  const float* bq   = (const float*)d_in[4];
  const float* wk   = (const float*)d_in[5];
  const float* bk   = (const float*)d_in[6];
  const float* wv   = (const float*)d_in[7];
  const float* bv   = (const float*)d_in[8];
  const float* wo   = (const float*)d_in[9];
  const float* bo   = (const float*)d_in[10];
  const float* ln2s = (const float*)d_in[11];
  const float* ln2b = (const float*)d_in[12];
  const float* w1   = (const float*)d_in[13];
  const float* b1   = (const float*)d_in[14];
  const float* w2   = (const float*)d_in[15];
  const float* b2   = (const float*)d_in[16];

  float* out  = (float*)d_out;                           // (B,S,D); also x2 accumulator
  float* attn = (float*)d_out + (size_t)B_ * S_ * D_;    // (B,H,S,S) f32

  // ---- workspace: 24 MB (proven budget) ----
  char* ws = (char*)d_ws;
  __bf16* xln  = (__bf16*)(ws);                          // [0,2MB)
  __bf16* wqT  = (__bf16*)(ws + (2ull << 20));           // [2,3)
  __bf16* wkT  = (__bf16*)(ws + (3ull << 20));           // [3,4)
  __bf16* wvT  = (__bf16*)(ws + (4ull << 20));           // [4,5)
  __bf16* woT  = (__bf16*)(ws + (5ull << 20));           // [5,6)
  __bf16* w1T  = (__bf16*)(ws + (6ull << 20));           // [6,6.5)
  __bf16* w2T  = (__bf16*)(ws + (6ull << 20) + (512ull << 10));  // [6.5,7)
  __bf16* bufA = (__bf16*)(ws + (8ull << 20));           // [8,16): V8 (b0|b1) -> FC1 h
  __bf16* bufB = (__bf16*)(ws + (16ull << 20));          // [16,24): K8 (b0|b1) -> FC2 partials

  const dim3 blk(256);

  // 1) weights transpose + LN1 + out=x+bo init
  trans_cast<<<2688, blk, 0, stream>>>(wq, wk, wv, wo, w1, w2,
                                       wqT, wkT, wvT, woT, w1T, w2T,
                                       x, ln1s, ln1b, xln, bo, out);

  // 2) K projection both batches -> fp8-packed K8 in bufB (z = batch)
  gemm_nt<6, 4, __bf16><<<dim3(16, 16, 2), blk, 0, stream>>>(
      xln, wkT, bk, bufB, 256, 256, 256, (long)S_ * D_, 0);

  // 3) V projection both batches -> fp8-packed V8 in bufA (operand swap; z = batch)
  gemm_nt<8, 4, __bf16><<<dim3(16, 16, 2), blk, 0, stream>>>(
      wvT, xln, bv, bufA, 256, 256, 256, 0, (long)S_ * D_);

  // 4) fused flash attention, both batches: 1024 blocks (2/CU), XCD-affine
  attn_fused<<<1024, dim3(512), 0, stream>>>(
      xln, wqT, bq, (const unsigned char*)bufB, (const unsigned char*)bufA,
      woT, attn, out);

  // 5) ln2 over x2 (accumulated in out)
  ln_cast_kernel<<<1024, blk, 0, stream>>>(out, ln2s, ln2b, xln);

  // 6) FC1: h = gelu(xln2 @ w1 + b1) -> bufA
  gemm_nt<5, 2, __bf16><<<dim3(8, 64, 1), blk, 0, stream>>>(
      xln, w1T, b1, bufA, 256, 256, 256, 0, 0);

  // 7) FC2 split-K (kz=2): partials -> bufB
  gemm_nt<7, 2, __bf16><<<dim3(2, 64, 2), blk, 0, stream>>>(
      bufA, w2T, nullptr, (float*)bufB, 512, 1024, 1024, 512, 512);

  // 8) reduce with residual (in-place on out)
  reduce_addk<<<1024, blk, 0, stream>>>((float*)bufB, out, b2, out, 262144, 2);
}

// Round 22
// 203.090 us; speedup vs baseline: 1.0323x; 1.0323x over previous
//
#include <hip/hip_runtime.h>
#include <hip/hip_bf16.h>
#include <hip/hip_fp8.h>

// Problem constants
#define B_ 2
#define S_ 2048
#define D_ 256
#define H_ 8
#define E_ 256
#define F_ 1024

typedef __attribute__((ext_vector_type(8))) __bf16 b16x8;
typedef __attribute__((ext_vector_type(4))) __bf16 b16x4;
typedef __attribute__((ext_vector_type(4))) float f32x4;
typedef __attribute__((ext_vector_type(2))) float f32x2;

__device__ inline float wred_sum(float v) {
#pragma unroll
  for (int o = 32; o > 0; o >>= 1) v += __shfl_xor(v, o);
  return v;
}

__device__ inline unsigned char f8(float v) {
  return __hip_fp8_e4m3(v).__x;
}
__device__ inline float e4f(unsigned char u) {
  __hip_fp8_e4m3 t;
  t.__x = (__hip_fp8_storage_t)u;
  return (float)t;
}

// HW fp8 pack/unpack (gfx950); HI must be a compile-time constant (instr modifier)
template <bool HI>
__device__ inline unsigned f8pack2(float a, float b, unsigned old) {
#if __has_builtin(__builtin_amdgcn_cvt_pk_fp8_f32)
  return (unsigned)__builtin_amdgcn_cvt_pk_fp8_f32(a, b, (int)old, HI);
#else
  unsigned lo = (unsigned)f8(a) | ((unsigned)f8(b) << 8);
  return HI ? ((old & 0x0000FFFFu) | (lo << 16)) : ((old & 0xFFFF0000u) | lo);
#endif
}
template <bool HI>
__device__ inline f32x2 f8unpack2(unsigned u) {
#if __has_builtin(__builtin_amdgcn_cvt_pk_f32_fp8)
  return __builtin_amdgcn_cvt_pk_f32_fp8((int)u, HI);
#else
  f32x2 r;
  unsigned s = HI ? (u >> 16) : u;
  r[0] = e4f(s & 255);
  r[1] = e4f((s >> 8) & 255);
  return r;
#endif
}

// chunk swizzle for fp8 tiles (8B chunks): bijective, spreads banks by row
#define SWC(ch, row) ((ch) ^ (((row) & 15) << 1))

// ---------------- LayerNorm (+cast to bf16): one row of 256 per wave ----------------
__device__ inline void ln_row(const float* __restrict__ x, const float* __restrict__ scale,
                              const float* __restrict__ bias, __bf16* __restrict__ out,
                              int row, int lane) {
  const float4 v = *(const float4*)(x + (size_t)row * D_ + lane * 4);
  float s = v.x + v.y + v.z + v.w;
  float q = v.x * v.x + v.y * v.y + v.z * v.z + v.w * v.w;
  s = wred_sum(s);
  q = wred_sum(q);
  const float mean = s * (1.0f / D_);
  const float var = q * (1.0f / D_) - mean * mean;
  const float rstd = rsqrtf(var + 1e-6f);
  const float4 sc = *(const float4*)(scale + lane * 4);
  const float4 bi = *(const float4*)(bias + lane * 4);
  b16x4 o;
  o[0] = (__bf16)((v.x - mean) * rstd * sc.x + bi.x);
  o[1] = (__bf16)((v.y - mean) * rstd * sc.y + bi.y);
  o[2] = (__bf16)((v.z - mean) * rstd * sc.z + bi.z);
  o[3] = (__bf16)((v.w - mean) * rstd * sc.w + bi.w);
  *(b16x4*)(out + (size_t)row * D_ + lane * 4) = o;
}

__global__ __launch_bounds__(256) void ln_cast_kernel(
    const float* __restrict__ x, const float* __restrict__ scale,
    const float* __restrict__ bias, __bf16* __restrict__ out) {
  ln_row(x, scale, bias, out, blockIdx.x * 4 + (threadIdx.x >> 6), threadIdx.x & 63);
}

// ---------------- Weight transpose-cast + LN1 + out-init ----------------
// bid<640: 64x64 weight tiles. [640,1664): LN1 rows. [1664,2688): out = x + bo.
__global__ __launch_bounds__(256) void trans_cast(
    const float* wq, const float* wk, const float* wv, const float* wo,
    const float* w1, const float* w2,
    __bf16* wqT, __bf16* wkT, __bf16* wvT, __bf16* woT, __bf16* w1T, __bf16* w2T,
    const float* x, const float* ln1s, const float* ln1b, __bf16* xln,
    const float* bo, float* outp) {
  __shared__ float lds[64][65];
  int bid = blockIdx.x;
  const int t = threadIdx.x;
  if (bid >= 1664) {  // out init: out = x + bo (1M floats, float4)
    const int i = (bid - 1664) * 256 + t;
    const float4 xb = ((const float4*)x)[i];
    const float4 bb = ((const float4*)bo)[i & 63];
    float4 o;
    o.x = xb.x + bb.x; o.y = xb.y + bb.y; o.z = xb.z + bb.z; o.w = xb.w + bb.w;
    ((float4*)outp)[i] = o;
    return;
  }
  if (bid >= 640) {  // LN1: 4 rows per block
    ln_row(x, ln1s, ln1b, xln, (bid - 640) * 4 + (t >> 6), t & 63);
    return;
  }
  const float* in;
  __bf16* out;
  int R, C, tidx;
  if (bid < 128) { in = wq; out = wqT; R = 256; C = 2048; tidx = bid; }
  else if (bid < 256) { in = wk; out = wkT; R = 256; C = 2048; tidx = bid - 128; }
  else if (bid < 384) { in = wv; out = wvT; R = 256; C = 2048; tidx = bid - 256; }
  else if (bid < 512) { in = wo; out = woT; R = 2048; C = 256; tidx = bid - 384; }
  else if (bid < 576) { in = w1; out = w1T; R = 256; C = 1024; tidx = bid - 512; }
  else { in = w2; out = w2T; R = 1024; C = 256; tidx = bid - 576; }
  const int tiles_c = C >> 6;
  const int tr = tidx / tiles_c, tc = tidx % tiles_c;
  const int r = t >> 2, cq = t & 3;
  const float* base = in + (size_t)(tr * 64 + r) * C + tc * 64 + cq * 16;
#pragma unroll
  for (int i = 0; i < 4; ++i) {
    const float4 v = ((const float4*)base)[i];
    lds[r][cq * 16 + i * 4 + 0] = v.x;
    lds[r][cq * 16 + i * 4 + 1] = v.y;
    lds[r][cq * 16 + i * 4 + 2] = v.z;
    lds[r][cq * 16 + i * 4 + 3] = v.w;
  }
  __syncthreads();
  const int oc = t >> 2;
  __bf16* ob = out + (size_t)(tc * 64 + oc) * R + tr * 64 + cq * 16;
  b16x8 o0, o1;
#pragma unroll
  for (int i = 0; i < 8; ++i) o0[i] = (__bf16)lds[cq * 16 + i][oc];
#pragma unroll
  for (int i = 0; i < 8; ++i) o1[i] = (__bf16)lds[cq * 16 + 8 + i][oc];
  ((b16x8*)ob)[0] = o0;
  ((b16x8*)ob)[1] = o1;
}

__device__ inline float gelu_f(float u) {
  const float c = 0.7978845608028654f;  // sqrt(2/pi)
  float t = tanhf(c * (u + 0.044715f * u * u * u));
  return 0.5f * u * (1.0f + t);
}

// ---------------- NT GEMM: C = A(MxK) * Bt(NxK)^T, bf16 MFMA, fp32 acc ----------------
// EPI: 5=fc1 gelu(acc+bias)->bf16 (ld F)
//      6=K proj -> fp8-packed K8 (+z*4MB batch offset)
//      7=split-K partial f32 (z = split index)
//      8=V proj -> fp8-packed V8 (+z*4MB batch offset)
#define BN 128
#define BK 64

template <int EPI, int MT, typename TA>
__global__ __launch_bounds__(256) void gemm_nt(
    const TA* __restrict__ A, const __bf16* __restrict__ Bt,
    const float* __restrict__ bias, void* __restrict__ Cout,
    int K, int lda, int ldb, long strideAz, long strideBz) {
  constexpr int BM = MT * 32;
  __shared__ __attribute__((aligned(16))) __bf16 As[BM * BK];
  __shared__ __attribute__((aligned(16))) __bf16 Bs[BN * BK];
  const int tid = threadIdx.x;
  const int lane = tid & 63;
  const int wid = tid >> 6;
  const int wr = wid >> 1, wc = wid & 1;
  const int m0 = blockIdx.y * BM, n0 = blockIdx.x * BN;
  const TA* Ab = A + (size_t)blockIdx.z * strideAz;
  const __bf16* Btb = Bt + (size_t)blockIdx.z * strideBz;

  f32x4 acc[MT][4] = {};

  for (int k0 = 0; k0 < K; k0 += BK) {
    __syncthreads();
#pragma unroll
    for (int i = 0; i < MT; ++i) {
      const int cid = tid + i * 256;
      const int row = cid >> 3, ch = cid & 7;
      const int sw = ch ^ (row & 7);
      b16x8 av = *(const b16x8*)(Ab + (size_t)(m0 + row) * lda + k0 + ch * 8);
      *(b16x8*)(As + row * BK + sw * 8) = av;
    }
#pragma unroll
    for (int i = 0; i < 4; ++i) {
      const int cid = tid + i * 256;
      const int row = cid >> 3, ch = cid & 7;
      const int sw = ch ^ (row & 7);
      const b16x8 bv = *(const b16x8*)(Btb + (size_t)(n0 + row) * ldb + k0 + ch * 8);
      *(b16x8*)(Bs + row * BK + sw * 8) = bv;
    }
    __syncthreads();
#pragma unroll
    for (int ks = 0; ks < 2; ++ks) {
      b16x8 af[MT], bfr[4];
#pragma unroll
      for (int m = 0; m < MT; ++m) {
        const int r = wr * (MT * 16) + m * 16 + (lane & 15);
        const int ch = ks * 4 + (lane >> 4);
        af[m] = *(const b16x8*)(As + r * BK + (ch ^ (r & 7)) * 8);
      }
#pragma unroll
      for (int n = 0; n < 4; ++n) {
        const int r = wc * 64 + n * 16 + (lane & 15);
        const int ch = ks * 4 + (lane >> 4);
        bfr[n] = *(const b16x8*)(Bs + r * BK + (ch ^ (r & 7)) * 8);
      }
#pragma unroll
      for (int m = 0; m < MT; ++m)
#pragma unroll
        for (int n = 0; n < 4; ++n)
          acc[m][n] = __builtin_amdgcn_mfma_f32_16x16x32_bf16(af[m], bfr[n],
                                                              acc[m][n], 0, 0, 0);
    }
  }

  const int z = blockIdx.z;
#pragma unroll
  for (int m = 0; m < MT; ++m) {
    const int gr0 = m0 + wr * (MT * 16) + m * 16 + (lane >> 4) * 4;
#pragma unroll
    for (int n = 0; n < 4; ++n) {
      const int gc = n0 + wc * 64 + n * 16 + (lane & 15);
#pragma unroll
      for (int r = 0; r < 4; ++r) {
        float v = acc[m][n][r];
        const int grow = gr0 + r;
        if constexpr (EPI == 5) {
          ((__bf16*)Cout)[(size_t)grow * F_ + gc] = (__bf16)gelu_f(v + bias[gc]);
        } else if constexpr (EPI == 6) {
          v += bias[gc];
          const int hh = gc >> 8, e = gc & 255, key = grow;
          const size_t addr =
              ((((size_t)hh * 128 + (key >> 4)) * 8 + (e >> 5)) * 64 +
               (((e >> 3) & 3) * 16 + (key & 15))) * 8 + (e & 7);
          ((unsigned char*)Cout)[(size_t)z * 4194304 + addr] = f8(v);
        } else if constexpr (EPI == 8) {
          v += bias[grow];
          const int hh = grow >> 8, e = grow & 255, key = gc;
          const size_t addr =
              ((((size_t)hh * 16 + (e >> 4)) * 64 + (key >> 5)) * 64 +
               (((key >> 3) & 3) * 16 + (e & 15))) * 8 + (key & 7);
          ((unsigned char*)Cout)[(size_t)z * 4194304 + addr] = f8(v);
        } else {  // 7: split-K partial
          ((float*)Cout)[((size_t)z * gridDim.y * BM + grow) * 256 + gc] = v;
        }
      }
    }
  }
}

// ---------------- Fused flash attention + WO partial: 64 q-rows, 8 waves, fp8 ----------------
// 512 threads, grid 512 = both batches. XCD-affine: h = bid&7; b = (bid>>3)&1; m0 = (bid>>4)*64.
// P1 processes keys in 4 chunks of 64 (acc1[4][4] = 64 VGPRs live) to avoid scratch spills.
// Best measured config (round 20: 203.96 us).
__global__ __launch_bounds__(512, 1) void attn_fused(
    const __bf16* __restrict__ xln, const __bf16* __restrict__ wqT,
    const float* __restrict__ bq, const unsigned char* __restrict__ k8,
    const unsigned char* __restrict__ v8, const __bf16* __restrict__ woT,
    float* __restrict__ attn, float* __restrict__ out) {
  __shared__ __attribute__((aligned(16))) unsigned char p_s[64 * 2048];  // 128 KB (vb overlays)
  __shared__ __attribute__((aligned(16))) unsigned char q_s[64 * 256];   // 16 KB
  __shared__ float l_s[64][9];
  __shared__ float inv_s[64];
  __bf16* vb = (__bf16*)p_s;  // val (64x256 bf16 = 32KB) overlays p_s after P2 reads

  const int tid = threadIdx.x, lane = tid & 63, wid = tid >> 6;
  const int h = blockIdx.x & 7;
  const int b = (blockIdx.x >> 3) & 1;
  const int m0 = (blockIdx.x >> 4) * 64;
  const int l15 = lane & 15, l4 = lane >> 4;
  const int e0w = wid * 32;
  const __bf16* xln_b = xln + (size_t)b * S_ * D_;
  float* attn_b = attn + (size_t)b * H_ * S_ * S_;
  float* out_b = out + (size_t)b * S_ * D_;
  const unsigned char* khp = k8 + (size_t)b * 4194304 + (size_t)h * 524288;
  const unsigned char* vhp = v8 + (size_t)b * 4194304 + (size_t)h * 524288;

  // ---- P0 (swapped): q(64xE) -> q_s fp8, packed u32 stores ----
  {
    f32x4 aq[4][2] = {};  // [m: q-tile][n: e-tile]; D[e_local][q]
#pragma unroll
    for (int ks = 0; ks < 8; ++ks) {
      const int d0 = ks * 32 + l4 * 8;
      b16x8 aw[2], bx[4];
#pragma unroll
      for (int n = 0; n < 2; ++n)
        aw[n] = *(const b16x8*)(wqT + (size_t)(h * E_ + e0w + n * 16 + l15) * D_ + d0);
#pragma unroll
      for (int m = 0; m < 4; ++m)
        bx[m] = *(const b16x8*)(xln_b + (size_t)(m0 + m * 16 + l15) * D_ + d0);
#pragma unroll
      for (int m = 0; m < 4; ++m)
#pragma unroll
        for (int n = 0; n < 2; ++n)
          aq[m][n] = __builtin_amdgcn_mfma_f32_16x16x32_bf16(aw[n], bx[m], aq[m][n], 0, 0, 0);
    }
#pragma unroll
    for (int m = 0; m < 4; ++m)
#pragma unroll
      for (int n = 0; n < 2; ++n) {
        const int row = m * 16 + l15;               // q-row
        const int e = e0w + n * 16 + l4 * 4;        // 4 consecutive e
        unsigned u = f8pack2<false>(aq[m][n][0] + bq[h * E_ + e],
                                    aq[m][n][1] + bq[h * E_ + e + 1], 0u);
        u = f8pack2<true>(aq[m][n][2] + bq[h * E_ + e + 2],
                          aq[m][n][3] + bq[h * E_ + e + 3], u);
        *(unsigned*)(q_s + row * 256 + SWC(e >> 3, row) * 8 + (e & 7)) = u;
      }
  }
  __syncthreads();

  // ---- P1 (swapped): S^T = K.Q -> P~ fp8 packed u32; 4 chunks of 64 keys ----
  float lsum[4] = {};
  for (int kc = 0; kc < 4; ++kc) {
    const int kb = wid * 256 + kc * 64;
    const int kt0 = kb >> 4;
    f32x4 acc1[4][4] = {};  // [m: q-tile][n: key-tile]; 64 VGPRs live
#pragma unroll
    for (int ks = 0; ks < 8; ++ks) {
      long long ak[4], qf[4];
#pragma unroll
      for (int n = 0; n < 4; ++n)
        ak[n] = *(const long long*)(khp + ((size_t)(kt0 + n) * 8 + ks) * 512 + lane * 8);
#pragma unroll
      for (int m = 0; m < 4; ++m) {
        const int row = m * 16 + l15;
        qf[m] = *(const long long*)(q_s + row * 256 + SWC(ks * 4 + l4, row) * 8);
      }
      __builtin_amdgcn_s_setprio(1);
#pragma unroll
      for (int m = 0; m < 4; ++m)
#pragma unroll
        for (int n = 0; n < 4; ++n)
          acc1[m][n] = __builtin_amdgcn_mfma_f32_16x16x32_fp8_fp8(ak[n], qf[m],
                                                                  acc1[m][n], 0, 0, 0);
      __builtin_amdgcn_s_setprio(0);
    }
#pragma unroll
    for (int m = 0; m < 4; ++m) {
      const int row = m * 16 + l15;  // q-row
#pragma unroll
      for (int n = 0; n < 4; ++n) {
        const int key = kb + n * 16 + l4 * 4;  // 4 consecutive keys
        const float p0 = __expf(acc1[m][n][0] * 0.0625f);
        const float p1 = __expf(acc1[m][n][1] * 0.0625f);
        const float p2 = __expf(acc1[m][n][2] * 0.0625f);
        const float p3 = __expf(acc1[m][n][3] * 0.0625f);
        unsigned u = f8pack2<false>(p0, p1, 0u);
        u = f8pack2<true>(p2, p3, u);
        *(unsigned*)(p_s + row * 2048 + SWC(key >> 3, row) * 8 + (key & 7)) = u;
        lsum[m] += (p0 + p1) + (p2 + p3);
      }
    }
  }
#pragma unroll
  for (int m = 0; m < 4; ++m) {
    float s = lsum[m];
    s += __shfl_xor(s, 16);
    s += __shfl_xor(s, 32);
    if (l4 == 0) l_s[m * 16 + l15][wid] = s;
  }
  __syncthreads();
  if (tid < 64) {
    float s = 0.f;
#pragma unroll
    for (int w = 0; w < 8; ++w) s += l_s[tid][w];
    inv_s[tid] = 1.0f / s;
  }
  __syncthreads();

  // ---- P2: PV fp8 (wave owns 32 e-cols) + interleaved normalized-attn writes ----
  f32x4 acc2[4][2] = {};
  {
    const int prow = tid >> 3, pc = tid & 7;  // 8 thr/row; 32 chunk-slices of 8 keys
    const float pinv = inv_s[prow];
    float* arow = attn_b + ((size_t)h * S_ + m0 + prow) * S_;
#pragma unroll 2
    for (int kt = 0; kt < 64; ++kt) {
      long long paf[4], bvf[2];
#pragma unroll
      for (int m = 0; m < 4; ++m) {
        const int row = m * 16 + l15;
        paf[m] = *(const long long*)(p_s + row * 2048 + SWC(kt * 4 + l4, row) * 8);
      }
#pragma unroll
      for (int n = 0; n < 2; ++n)
        bvf[n] = *(const long long*)(vhp + ((size_t)(wid * 2 + n) * 64 + kt) * 512 + lane * 8);
      __builtin_amdgcn_s_setprio(1);
#pragma unroll
      for (int m = 0; m < 4; ++m)
#pragma unroll
        for (int n = 0; n < 2; ++n)
          acc2[m][n] = __builtin_amdgcn_mfma_f32_16x16x32_fp8_fp8(paf[m], bvf[n],
                                                                  acc2[m][n], 0, 0, 0);
      __builtin_amdgcn_s_setprio(0);

      if ((kt & 1) == 0) {  // one 8-key slice per 2 PV iterations (32 total)
        const int ch = pc + (kt >> 1) * 8;
        const unsigned* pu = (const unsigned*)(p_s + prow * 2048 + SWC(ch, prow) * 8);
        const unsigned u0 = pu[0], u1 = pu[1];
        const f32x2 a0 = f8unpack2<false>(u0), a1 = f8unpack2<true>(u0);
        const f32x2 a2 = f8unpack2<false>(u1), a3 = f8unpack2<true>(u1);
        f32x4 o0, o1;
        o0[0] = a0[0] * pinv; o0[1] = a0[1] * pinv;
        o0[2] = a1[0] * pinv; o0[3] = a1[1] * pinv;
        o1[0] = a2[0] * pinv; o1[1] = a2[1] * pinv;
        o1[2] = a3[0] * pinv; o1[3] = a3[1] * pinv;
        const int key0 = ch * 8;
        *(f32x4*)(arow + key0) = o0;       // plain cached store (L2 write-combining)
        *(f32x4*)(arow + key0 + 4) = o1;
      }
    }
  }
  __syncthreads();  // all p_s reads done before vb (alias) is written

#pragma unroll
  for (int m = 0; m < 4; ++m)
#pragma unroll
    for (int n = 0; n < 2; ++n)
#pragma unroll
      for (int r = 0; r < 4; ++r) {
        const int row = m * 16 + l4 * 4 + r;
        const int e = e0w + n * 16 + l15;
        vb[row * 256 + (e ^ ((row & 7) << 3))] = (__bf16)(acc2[m][n][r] * inv_s[row]);
      }
  __syncthreads();  // vb read cross-wave below

  // ---- P2b: WO partial (bf16): wave owns 32 d-cols, K = full 256 e ----
  {
    f32x4 acc3[4][2] = {};
#pragma unroll
    for (int ks = 0; ks < 8; ++ks) {
      const int ch = ks * 4 + l4;
      b16x8 vaf[4], wf[2];
#pragma unroll
      for (int m = 0; m < 4; ++m) {
        const int row = m * 16 + l15;
        vaf[m] = *(const b16x8*)(vb + row * 256 + ((ch ^ (row & 7)) * 8));
      }
      const int ec = ks * 32 + l4 * 8;
#pragma unroll
      for (int n = 0; n < 2; ++n)
        wf[n] = *(const b16x8*)(woT + (size_t)(e0w + n * 16 + l15) * 2048 + h * E_ + ec);
#pragma unroll
      for (int m = 0; m < 4; ++m)
#pragma unroll
        for (int n = 0; n < 2; ++n)
          acc3[m][n] = __builtin_amdgcn_mfma_f32_16x16x32_bf16(vaf[m], wf[n], acc3[m][n], 0, 0, 0);
    }
#pragma unroll
    for (int m = 0; m < 4; ++m)
#pragma unroll
      for (int n = 0; n < 2; ++n)
#pragma unroll
        for (int r = 0; r < 4; ++r) {
          const int row = m * 16 + l4 * 4 + r;
          const int d = e0w + n * 16 + l15;
          atomicAdd(out_b + (size_t)(m0 + row) * D_ + d, acc3[m][n][r]);
        }
  }
}

// ---------------- out = resid + bias + sum_z pbuf[z] (N=256 cols) ----------------
__global__ __launch_bounds__(256) void reduce_addk(
    const float* __restrict__ pbuf, const float* __restrict__ resid,
    const float* __restrict__ bias, float* __restrict__ out, int mn4, int kz) {
  const int i = blockIdx.x * 256 + threadIdx.x;
  if (i >= mn4) return;
  float4 s = ((const float4*)resid)[i];
  const float4 bb = ((const float4*)bias)[i & 63];
  s.x += bb.x; s.y += bb.y; s.z += bb.z; s.w += bb.w;
  for (int z = 0; z < kz; ++z) {
    const float4 p = ((const float4*)pbuf)[(size_t)z * mn4 + i];
    s.x += p.x; s.y += p.y; s.z += p.z; s.w += p.w;
  }
  ((float4*)out)[i] = s;
}

extern "C" void kernel_launch(void* const* d_in, const int* in_sizes, int n_in,
                              void* d_out, int out_size, void* d_ws, size_t ws_size,
                              hipStream_t stream) {
  (void)in_sizes; (void)n_in; (void)out_size; (void)ws_size;
  const float* x    = (const float*)d_in[0];
  const float* ln1s = (const float*)d_in[1];
  const float* ln1b = (const float*)d_in[2];
  const float* wq   = (const float*)d_in[3];
  const float* bq   = (const float*)d_in[4];
  const float* wk   = (const float*)d_in[5];
  const float* bk   = (const float*)d_in[6];
  const float* wv   = (const float*)d_in[7];
  const float* bv   = (const float*)d_in[8];
  const float* wo   = (const float*)d_in[9];
  const float* bo   = (const float*)d_in[10];
  const float* ln2s = (const float*)d_in[11];
  const float* ln2b = (const float*)d_in[12];
  const float* w1   = (const float*)d_in[13];
  const float* b1   = (const float*)d_in[14];
  const float* w2   = (const float*)d_in[15];
  const float* b2   = (const float*)d_in[16];

  float* out  = (float*)d_out;                           // (B,S,D); also x2 accumulator
  float* attn = (float*)d_out + (size_t)B_ * S_ * D_;    // (B,H,S,S) f32

  // ---- workspace: 24 MB (proven budget) ----
  char* ws = (char*)d_ws;
  __bf16* xln  = (__bf16*)(ws);                          // [0,2MB)
  __bf16* wqT  = (__bf16*)(ws + (2ull << 20));           // [2,3)
  __bf16* wkT  = (__bf16*)(ws + (3ull << 20));           // [3,4)
  __bf16* wvT  = (__bf16*)(ws + (4ull << 20));           // [4,5)
  __bf16* woT  = (__bf16*)(ws + (5ull << 20));           // [5,6)
  __bf16* w1T  = (__bf16*)(ws + (6ull << 20));           // [6,6.5)
  __bf16* w2T  = (__bf16*)(ws + (6ull << 20) + (512ull << 10));  // [6.5,7)
  __bf16* bufA = (__bf16*)(ws + (8ull << 20));           // [8,16): V8 (b0|b1) -> FC1 h
  __bf16* bufB = (__bf16*)(ws + (16ull << 20));          // [16,24): K8 (b0|b1) -> FC2 partials

  const dim3 blk(256);

  // 1) weights transpose + LN1 + out=x+bo init
  trans_cast<<<2688, blk, 0, stream>>>(wq, wk, wv, wo, w1, w2,
                                       wqT, wkT, wvT, woT, w1T, w2T,
                                       x, ln1s, ln1b, xln, bo, out);

  // 2) K projection both batches -> fp8-packed K8 in bufB (z = batch)
  gemm_nt<6, 4, __bf16><<<dim3(16, 16, 2), blk, 0, stream>>>(
      xln, wkT, bk, bufB, 256, 256, 256, (long)S_ * D_, 0);

  // 3) V projection both batches -> fp8-packed V8 in bufA (operand swap; z = batch)
  gemm_nt<8, 4, __bf16><<<dim3(16, 16, 2), blk, 0, stream>>>(
      wvT, xln, bv, bufA, 256, 256, 256, 0, (long)S_ * D_);

  // 4) fused flash attention, both batches: 512 blocks, XCD-affine
  attn_fused<<<512, dim3(512), 0, stream>>>(
      xln, wqT, bq, (const unsigned char*)bufB, (const unsigned char*)bufA,
      woT, attn, out);

  // 5) ln2 over x2 (accumulated in out)
  ln_cast_kernel<<<1024, blk, 0, stream>>>(out, ln2s, ln2b, xln);

  // 6) FC1: h = gelu(xln2 @ w1 + b1) -> bufA
  gemm_nt<5, 2, __bf16><<<dim3(8, 64, 1), blk, 0, stream>>>(
      xln, w1T, b1, bufA, 256, 256, 256, 0, 0);

  // 7) FC2 split-K (kz=2): partials -> bufB
  gemm_nt<7, 2, __bf16><<<dim3(2, 64, 2), blk, 0, stream>>>(
      bufA, w2T, nullptr, (float*)bufB, 512, 1024, 1024, 512, 512);

  // 8) reduce with residual (in-place on out)
  reduce_addk<<<1024, blk, 0, stream>>>((float*)bufB, out, b2, out, 262144, 2);
}